// Round 4
// baseline (112.482 us; speedup 1.0000x reference)
//
#include <hip/hip_runtime.h>
#include <hip/hip_bf16.h>
#include <math.h>

// RelativeGeoSymLoss: B=8, N=4096 symmetric chamfer + trans L1.
// R4 structure: each wave owns RW=16 rows; its 64 lanes split the m-dim.
// B-side streams via coalesced global float4 loads (no LDS, no syncthreads
// in the hot loop, no global atomicMin). Row min finished in-wave via
// shfl_xor butterfly; sqrt+sum fused; one atomicAdd per block.
// ws layout: pts [2][B][N] float4 (x,y,z,||.||^2) only.

#define TPB 256
#define RW  16   // rows per wave

__device__ __forceinline__ void rel_tf(const float* __restrict__ Ra,
                                       const float* __restrict__ ta,
                                       const float* __restrict__ Rb,
                                       const float* __restrict__ tb,
                                       float* R, float* t) {
#pragma unroll
    for (int i = 0; i < 3; i++)
#pragma unroll
        for (int k = 0; k < 3; k++)
            R[i * 3 + k] = Ra[i * 3 + 0] * Rb[k * 3 + 0]
                         + Ra[i * 3 + 1] * Rb[k * 3 + 1]
                         + Ra[i * 3 + 2] * Rb[k * 3 + 2];
#pragma unroll
    for (int i = 0; i < 3; i++)
        t[i] = ta[i] - (R[i * 3 + 0] * tb[0] + R[i * 3 + 1] * tb[1]
                      + R[i * 3 + 2] * tb[2]);
}

// Fused: relative transforms (recomputed per thread, trivial) + point
// transform + out init (out[0]=0, out[1]=trans L1 loss).
__global__ void k_prep(const float* __restrict__ pred_rot,
                       const float* __restrict__ pred_trans,
                       const float* __restrict__ ctx_hyp_rot,
                       const float* __restrict__ ctx_hyp_trans,
                       const float* __restrict__ gt_rot,
                       const float* __restrict__ gt_trans,
                       const float* __restrict__ ctx_gt_rot,
                       const float* __restrict__ ctx_gt_trans,
                       const float* __restrict__ mp,
                       float4* __restrict__ pts,
                       float* __restrict__ out, int B, int N) {
    int idx = blockIdx.x * blockDim.x + threadIdx.x;
    if (idx >= B * N) return;
    int b = idx / N;
    float px = mp[idx * 3 + 0], py = mp[idx * 3 + 1], pz = mp[idx * 3 + 2];
    float R[9], t[3];
#pragma unroll
    for (int g = 0; g < 2; g++) {
        if (g == 0)
            rel_tf(pred_rot + b * 9, pred_trans + b * 3,
                   ctx_hyp_rot + b * 9, ctx_hyp_trans + b * 3, R, t);
        else
            rel_tf(gt_rot + b * 9, gt_trans + b * 3,
                   ctx_gt_rot + b * 9, ctx_gt_trans + b * 3, R, t);
        float x = R[0] * px + R[1] * py + R[2] * pz + t[0];
        float y = R[3] * px + R[4] * py + R[5] * pz + t[1];
        float z = R[6] * px + R[7] * py + R[8] * pz + t[2];
        pts[(size_t)g * B * N + idx] = make_float4(x, y, z, x * x + y * y + z * z);
    }
    if (idx == 0) {
        out[0] = 0.0f;
        float lt = 0.0f;
        for (int bb = 0; bb < B; bb++) {
            float Rp[9], tp[3], Rg[9], tg[3];
            rel_tf(pred_rot + bb * 9, pred_trans + bb * 3,
                   ctx_hyp_rot + bb * 9, ctx_hyp_trans + bb * 3, Rp, tp);
            rel_tf(gt_rot + bb * 9, gt_trans + bb * 3,
                   ctx_gt_rot + bb * 9, ctx_gt_trans + bb * 3, Rg, tg);
            lt += fabsf(tp[0] - tg[0]) + fabsf(tp[1] - tg[1]) + fabsf(tp[2] - tg[2]);
        }
        out[1] = lt / (float)(3 * B);
    }
}

// grid.x = 2 * B * (N / (TPB/64 * RW)); each wave: RW rows, lanes split m.
__global__ void __launch_bounds__(TPB, 4) k_chamfer(
        const float4* __restrict__ pts, float* __restrict__ out,
        int B, int N) {
    const int wave = threadIdx.x >> 6;
    const int lane = threadIdx.x & 63;
    const int rowsPerBlock = (TPB / 64) * RW;           // 64
    const int blocksPerB = N / rowsPerBlock;            // 64
    int bid = blockIdx.x;
    int dir = bid / (B * blocksPerB);
    int rem = bid % (B * blocksPerB);
    int b = rem / blocksPerB;
    int rblk = rem % blocksPerB;

    const float4* Ap = pts + ((size_t)dir * B + b) * N;
    const float4* Bp = pts + ((size_t)(1 - dir) * B + b) * N;
    int rowBase = rblk * rowsPerBlock + wave * RW;

    float a2x[RW], a2y[RW], a2z[RW], aw[RW], mn[RW];
#pragma unroll
    for (int r = 0; r < RW; r++) {
        float4 a = Ap[rowBase + r];     // same addr all lanes -> broadcast
        a2x[r] = -2.0f * a.x;
        a2y[r] = -2.0f * a.y;
        a2z[r] = -2.0f * a.z;
        aw[r] = a.w;
        mn[r] = INFINITY;
    }

    // main loop: lane L covers m = L, L+64, ... Coalesced dwordx4 loads.
#pragma unroll 4
    for (int mm = 0; mm < N; mm += 64) {
        float4 g = Bp[mm + lane];
#pragma unroll
        for (int r = 0; r < RW; r++) {
            float p = __builtin_fmaf(a2x[r], g.x, g.w);
            p = __builtin_fmaf(a2y[r], g.y, p);
            p = __builtin_fmaf(a2z[r], g.z, p);
            mn[r] = fminf(mn[r], p);
        }
    }

    // finish rows in-wave: butterfly min, then sqrt+accumulate.
    float s = 0.0f;
#pragma unroll
    for (int r = 0; r < RW; r++) {
        float m = mn[r];
#pragma unroll
        for (int off = 32; off > 0; off >>= 1)
            m = fminf(m, __shfl_xor(m, off, 64));
        s += sqrtf(fmaxf(m + aw[r], 0.0f));
    }

    __shared__ float red[TPB / 64];
    if (lane == 0) red[wave] = s;
    __syncthreads();
    if (threadIdx.x == 0) {
        float t = 0.0f;
#pragma unroll
        for (int w = 0; w < TPB / 64; w++) t += red[w];
        atomicAdd(&out[0], t / (float)(B * N));
    }
}

extern "C" void kernel_launch(void* const* d_in, const int* in_sizes, int n_in,
                              void* d_out, int out_size, void* d_ws, size_t ws_size,
                              hipStream_t stream) {
    const float* pred_rot      = (const float*)d_in[0];
    const float* pred_trans    = (const float*)d_in[1];
    const float* ctx_hyp_rot   = (const float*)d_in[2];
    const float* ctx_hyp_trans = (const float*)d_in[3];
    const float* gt_rot        = (const float*)d_in[4];
    const float* gt_trans      = (const float*)d_in[5];
    const float* ctx_gt_rot    = (const float*)d_in[6];
    const float* ctx_gt_trans  = (const float*)d_in[7];
    const float* model_points  = (const float*)d_in[8];

    int B = in_sizes[0] / 9;
    int N = in_sizes[8] / (3 * B);

    float4* pts = (float4*)d_ws;
    float*  out = (float*)d_out;

    k_prep<<<(B * N + TPB - 1) / TPB, TPB, 0, stream>>>(
        pred_rot, pred_trans, ctx_hyp_rot, ctx_hyp_trans,
        gt_rot, gt_trans, ctx_gt_rot, ctx_gt_trans,
        model_points, pts, out, B, N);

    int rowsPerBlock = (TPB / 64) * RW;                    // 64
    int grid = 2 * B * (N / rowsPerBlock);                 // 1024
    k_chamfer<<<grid, TPB, 0, stream>>>(pts, out, B, N);
}